// Round 4
// baseline (154.917 us; speedup 1.0000x reference)
//
#include <hip/hip_runtime.h>
#include <math.h>

// EPG GRE F0, NP2=64 pulses, V voxels.
// 16 lanes per voxel: lane sub (0..15) holds levels k = 16*j + sub, j<2.
// => 8192 waves (32/CU = full occupancy), 8 waves/SIMD.
// k-shift = DPP row_ror (16-lane row rotate, pure VALU, no LDS pipe):
//   row_ror:1  -> lane i reads lane (i-1)&15  (P: k <- k-1)
//   row_ror:15 -> lane i reads lane (i+1)&15  (M: k <- k+1)
// RF coeffs precomputed to LDS once, broadcast-read + readfirstlane -> SGPRs.
// Exact truncation (proof as rounds 1-3): matvec only where 16j <= b=min(p,63-p);
// shift full width. Up-ramp dead levels are exactly zero; down-ramp junk stays
// strictly above the shrinking live cone and can never reach F0.

#define NP2 64
#define SLOTS 2

#define ROR1  0x121   // row_ror:1  : src lane = (i-1) & 15
#define ROR15 0x12F   // row_ror:15 : src lane = (i+1) & 15

template<int CTRL>
__device__ __forceinline__ float rowrot(float x) {
    return __int_as_float(
        __builtin_amdgcn_mov_dpp(__float_as_int(x), CTRL, 0xF, 0xF, true));
}

__device__ __forceinline__ float rfl(float x) {   // wave-uniform -> SGPR
    return __int_as_float(__builtin_amdgcn_readfirstlane(__float_as_int(x)));
}

__global__ __launch_bounds__(256, 8) void epg_kernel(
    const float* __restrict__ theta_re,
    const float* __restrict__ theta_im,
    const float* __restrict__ TRp,
    const float* __restrict__ qmaps,
    float* __restrict__ out, int V)
{
    const int t = threadIdx.x;
    const int sub = t & 15;           // lane within voxel group
    const int vloc = t >> 4;          // 0..15 local voxel
    const int v = blockIdx.x * 16 + vloc;

    __shared__ __align__(16) float rf[NP2][8]; // [p]: ca2, ca, t1, t2, t3, t4, h3, h4
    __shared__ __align__(16) float buf[16][68];

    // ---- prologue: lane p computes pulse p's 8 RF coefficients ----
    if (t < NP2) {
        const float tre = theta_re[t], tim = theta_im[t];
        const float a2 = tre * tre + tim * tim;
        const float inva = __frsqrt_rn(a2);        // |theta| >= 0.1
        const float a = a2 * inva;
        const float c = tre * inva, s = tim * inva;
        float sa, ca;
        __sincosf(a, &sa, &ca);
        const float ca2 = 0.5f + 0.5f * ca;        // cos^2(a/2)
        const float sa2 = 0.5f - 0.5f * ca;        // sin^2(a/2)
        const float t1 = (c * c - s * s) * sa2;    // cos(2phi)*sin^2(a/2)
        const float t2 = (2.f * c * s) * sa2;      // sin(2phi)*sin^2(a/2)
        const float t3 = s * sa;
        const float t4 = c * sa;
        rf[t][0] = ca2; rf[t][1] = ca; rf[t][2] = t1; rf[t][3] = t2;
        rf[t][4] = t3;  rf[t][5] = t4; rf[t][6] = 0.5f * t3; rf[t][7] = 0.5f * t4;
    }

    const float PD = qmaps[v];
    const float T1 = qmaps[V + v];
    const float T2 = qmaps[2 * V + v];
    const float tr = TRp[0];
    const float E1 = __expf(-tr / T1);
    const float E2 = __expf(-tr / T2);
    const float rE1s = (sub == 0) ? (1.0f - E1) : 0.0f;

    float Pr[SLOTS], Pi[SLOTS], Mr[SLOTS], Mi[SLOTS], Zr[SLOTS], Zi[SLOTS];
#pragma unroll
    for (int j = 0; j < SLOTS; ++j) {
        Pr[j] = 0.f; Pi[j] = 0.f; Mr[j] = 0.f; Mi[j] = 0.f; Zr[j] = 0.f; Zi[j] = 0.f;
    }
    if (sub == 0) Zr[0] = 1.0f;

    __syncthreads();

    const bool s0 = (sub == 0);
    const bool s15 = (sub == 15);

    for (int p = 0; p < NP2; ++p) {
        const float4 c0 = *(const float4*)&rf[p][0];
        const float4 c1 = *(const float4*)&rf[p][4];
        const float ca2 = rfl(c0.x), ca = rfl(c0.y), t1 = rfl(c0.z), t2 = rfl(c0.w);
        const float t3 = rfl(c1.x), t4 = rfl(c1.y), h3 = rfl(c1.z), h4 = rfl(c1.w);

        const int b = min(p, 63 - p);      // live-level bound (wave-uniform)

        // ---- RF matvec on live slots ----
#pragma unroll
        for (int j = 0; j < SLOTS; ++j) {
            if (16 * j <= b) {
                const float pr = Pr[j], pi = Pi[j];
                const float mr = Mr[j], mi = Mi[j];
                const float zr = Zr[j], zi = Zi[j];
                const float npr =  ca2 * pr + t1 * mr - t2 * mi + t3 * zr + t4 * zi;
                const float npi =  ca2 * pi + t2 * mr + t1 * mi + t3 * zi - t4 * zr;
                const float nmr =  t1 * pr + t2 * pi + ca2 * mr + t3 * zr - t4 * zi;
                const float nmi = -t2 * pr + t1 * pi + ca2 * mi + t4 * zr + t3 * zi;
                const float nzr = -h3 * pr + h4 * pi - h3 * mr - h4 * mi + ca * zr;
                const float nzi = -h4 * pr - h3 * pi + h4 * mr - h3 * mi + ca * zi;
                Pr[j] = npr; Pi[j] = npi;
                Mr[j] = nmr; Mi[j] = nmi;
                Zr[j] = nzr; Zi[j] = nzi;
            }
        }
        // F0 = P'_0 lives on sub 0, slot 0
        if (s0) buf[vloc][p] = sqrtf(Pr[0] * Pr[0] + Pi[0] * Pi[0]) * PD;

        if (p < NP2 - 1) {
            // ---- relaxation (full width) ----
#pragma unroll
            for (int j = 0; j < SLOTS; ++j) {
                Pr[j] *= E2; Pi[j] *= E2;
                Mr[j] *= E2; Mi[j] *= E2;
                Zr[j] *= E1; Zi[j] *= E1;
            }
            Zr[0] += rE1s;

            // ---- shift via DPP row rotate (pure VALU) ----
            const float rPr0 = rowrot<ROR1>(Pr[0]),  rPi0 = rowrot<ROR1>(Pi[0]);
            const float rPr1 = rowrot<ROR1>(Pr[1]),  rPi1 = rowrot<ROR1>(Pi[1]);
            const float rMr0 = rowrot<ROR15>(Mr[0]), rMi0 = rowrot<ROR15>(Mi[0]);
            const float rMr1 = rowrot<ROR15>(Mr[1]), rMi1 = rowrot<ROR15>(Mi[1]);
            // P_k <- E2*P'_{k-1}: sub>=1 same slot; sub0 slot1 from slot0 (level 15->16);
            //                     sub0 slot0 = conj(new M_0) = conj(E2*M'_1)
            Pr[1] = s0 ?  rPr0 : rPr1;
            Pi[1] = s0 ?  rPi0 : rPi1;
            Pr[0] = s0 ?  rMr0 : rPr0;
            Pi[0] = s0 ? -rMi0 : rPi0;
            // M_k <- E2*M'_{k+1}: sub<=14 same slot; sub15 slot0 from slot1 (level 16->15);
            //                     sub15 slot1 = level 32 = 0 exactly
            Mr[0] = s15 ? rMr1 : rMr0;
            Mi[0] = s15 ? rMi1 : rMi0;
            Mr[1] = s15 ? 0.f : rMr1;
            Mi[1] = s15 ? 0.f : rMi1;
        }
    }

    // ---- coalesced output: block writes 16 voxels x 64 pulses ----
    __syncthreads();
    float4* out4 = (float4*)out;
    const int r = t >> 4;              // voxel row
    const int c = (t & 15) * 4;        // pulse col
    const float4 val = *(const float4*)&buf[r][c];   // row stride 272B = 16B-aligned
    out4[blockIdx.x * 256 + t] = val;
}

extern "C" void kernel_launch(void* const* d_in, const int* in_sizes, int n_in,
                              void* d_out, int out_size, void* d_ws, size_t ws_size,
                              hipStream_t stream) {
    const float* theta_re = (const float*)d_in[0];
    const float* theta_im = (const float*)d_in[1];
    const float* TRp      = (const float*)d_in[2];
    const float* qmaps    = (const float*)d_in[3];
    float* out = (float*)d_out;
    const int V = in_sizes[3] / 3;             // qmaps is [3, V, 1]
    epg_kernel<<<dim3(V / 16), dim3(256), 0, stream>>>(theta_re, theta_im, TRp, qmaps, out, V);
}

// Round 6
// 153.848 us; speedup vs baseline: 1.0069x; 1.0069x over previous
//
#include <hip/hip_runtime.h>
#include <math.h>

// EPG GRE F0, NP2=64 pulses, V voxels.
// 16 lanes per voxel: lane sub (0..15) holds levels k = 16*j + sub, j<2.
// k-shift = DPP row_ror (16-lane row rotate): ROR1 (P: from lane-1), ROR15 (M: from lane+1).
// ROUND 6: identical semantics to round 4 (passed, 100us), ONLY change:
// #pragma unroll 1 on the p-loop so the body (~1 KB) stays L1I-resident.
// R2-R4 were flat at ~100-110us across occupancy 17/30/54% and ~1.8x differing
// instruction counts -- fingerprint of an instruction-fetch floor from the
// 45-77 KB fully-unrolled bodies (L1I = 32 KB).
// Exactness (as R1-R4, passing): levels > p are exactly zero on the up-ramp;
// on the down-ramp, a state at level k needs k down-shifts (one per pulse, M path)
// to reach F0, so anything at level >= 16 after p = 47 is provably dead.

#define NP2 64
#define ROR1  0x121   // row_ror:1  : dest lane i <- lane (i-1) & 15
#define ROR15 0x12F   // row_ror:15 : dest lane i <- lane (i+1) & 15

template<int CTRL>
__device__ __forceinline__ float rowrot(float x) {
    return __int_as_float(
        __builtin_amdgcn_mov_dpp(__float_as_int(x), CTRL, 0xF, 0xF, true));
}

__device__ __forceinline__ float rfl(float x) {   // wave-uniform -> SGPR
    return __int_as_float(__builtin_amdgcn_readfirstlane(__float_as_int(x)));
}

__global__ __launch_bounds__(256, 8) void epg_kernel(
    const float* __restrict__ theta_re,
    const float* __restrict__ theta_im,
    const float* __restrict__ TRp,
    const float* __restrict__ qmaps,
    float* __restrict__ out, int V)
{
    const int t = threadIdx.x;
    const int sub = t & 15;           // lane within voxel group
    const int vloc = t >> 4;          // 0..15 local voxel
    const int v = blockIdx.x * 16 + vloc;

    __shared__ __align__(16) float rf[NP2][8]; // [p]: ca2, ca, t1, t2, t3, t4, h3, h4
    __shared__ __align__(16) float buf[16][68];

    // ---- prologue: lane p computes pulse p's 8 RF coefficients (once) ----
    if (t < NP2) {
        const float tre = theta_re[t], tim = theta_im[t];
        const float a2 = tre * tre + tim * tim;
        const float inva = __frsqrt_rn(a2);        // |theta| >= 0.1
        const float a = a2 * inva;
        const float c = tre * inva, s = tim * inva;
        float sa, ca;
        __sincosf(a, &sa, &ca);
        const float ca2 = 0.5f + 0.5f * ca;        // cos^2(a/2)
        const float sa2 = 0.5f - 0.5f * ca;        // sin^2(a/2)
        const float t1 = (c * c - s * s) * sa2;    // cos(2phi)*sin^2(a/2)
        const float t2 = (2.f * c * s) * sa2;      // sin(2phi)*sin^2(a/2)
        const float t3 = s * sa;
        const float t4 = c * sa;
        rf[t][0] = ca2; rf[t][1] = ca; rf[t][2] = t1; rf[t][3] = t2;
        rf[t][4] = t3;  rf[t][5] = t4; rf[t][6] = 0.5f * t3; rf[t][7] = 0.5f * t4;
    }

    const float PD = qmaps[v];
    const float T1 = qmaps[V + v];
    const float T2 = qmaps[2 * V + v];
    const float tr = TRp[0];
    const float E1 = __expf(-tr / T1);
    const float E2 = __expf(-tr / T2);
    const float rE1s = (sub == 0) ? (1.0f - E1) : 0.0f;

    // state: slot0 = levels sub, slot1 = levels 16+sub
    float P0r = 0.f, P0i = 0.f, M0r = 0.f, M0i = 0.f, Z0r = 0.f, Z0i = 0.f;
    float P1r = 0.f, P1i = 0.f, M1r = 0.f, M1i = 0.f, Z1r = 0.f, Z1i = 0.f;
    if (sub == 0) Z0r = 1.0f;

    __syncthreads();

    const bool s0 = (sub == 0);
    const bool s15 = (sub == 15);

#pragma unroll 1
    for (int p = 0; p < NP2; ++p) {
        const float4 c0 = *(const float4*)&rf[p][0];
        const float4 c1 = *(const float4*)&rf[p][4];
        const float ca2 = rfl(c0.x), ca = rfl(c0.y), t1 = rfl(c0.z), t2 = rfl(c0.w);
        const float t3 = rfl(c1.x), t4 = rfl(c1.y), h3 = rfl(c1.z), h4 = rfl(c1.w);

        // ---- RF matvec, slot 0 (levels 0..15: always live) ----
        {
            const float pr = P0r, pi = P0i;
            const float mr = M0r, mi = M0i;
            const float zr = Z0r, zi = Z0i;
            P0r =  ca2 * pr + t1 * mr - t2 * mi + t3 * zr + t4 * zi;
            P0i =  ca2 * pi + t2 * mr + t1 * mi + t3 * zi - t4 * zr;
            M0r =  t1 * pr + t2 * pi + ca2 * mr + t3 * zr - t4 * zi;
            M0i = -t2 * pr + t1 * pi + ca2 * mi + t4 * zr + t3 * zi;
            Z0r = -h3 * pr + h4 * pi - h3 * mr - h4 * mi + ca * zr;
            Z0i = -h4 * pr - h3 * pi + h4 * mr - h3 * mi + ca * zi;
        }
        // ---- RF matvec, slot 1 (levels 16..31: live iff 16 <= min(p,63-p)) ----
        if (p >= 16 && p <= 47) {
            const float pr = P1r, pi = P1i;
            const float mr = M1r, mi = M1i;
            const float zr = Z1r, zi = Z1i;
            P1r =  ca2 * pr + t1 * mr - t2 * mi + t3 * zr + t4 * zi;
            P1i =  ca2 * pi + t2 * mr + t1 * mi + t3 * zi - t4 * zr;
            M1r =  t1 * pr + t2 * pi + ca2 * mr + t3 * zr - t4 * zi;
            M1i = -t2 * pr + t1 * pi + ca2 * mi + t4 * zr + t3 * zi;
            Z1r = -h3 * pr + h4 * pi - h3 * mr - h4 * mi + ca * zr;
            Z1i = -h4 * pr - h3 * pi + h4 * mr - h3 * mi + ca * zi;
        }
        // F0 = P'_0 lives on sub 0, slot 0
        if (s0) buf[vloc][p] = sqrtf(P0r * P0r + P0i * P0i) * PD;

        if (p < NP2 - 1) {
            // ---- relaxation (full width) ----
            P0r *= E2; P0i *= E2; M0r *= E2; M0i *= E2; Z0r *= E1; Z0i *= E1;
            P1r *= E2; P1i *= E2; M1r *= E2; M1i *= E2; Z1r *= E1; Z1i *= E1;
            Z0r += rE1s;

            // ---- shift via DPP row rotate (pure VALU) ----
            const float rP0r = rowrot<ROR1>(P0r),  rP0i = rowrot<ROR1>(P0i);
            const float rP1r = rowrot<ROR1>(P1r),  rP1i = rowrot<ROR1>(P1i);
            const float rM0r = rowrot<ROR15>(M0r), rM0i = rowrot<ROR15>(M0i);
            const float rM1r = rowrot<ROR15>(M1r), rM1i = rowrot<ROR15>(M1i);
            // P_k <- E2*P'_{k-1}: sub>=1 same slot; sub0 slot1 from slot0 (15->16);
            //                     sub0 slot0 = conj(new M_0) = conj(E2*M'_1)
            P1r = s0 ?  rP0r : rP1r;
            P1i = s0 ?  rP0i : rP1i;
            P0r = s0 ?  rM0r : rP0r;
            P0i = s0 ? -rM0i : rP0i;
            // M_k <- E2*M'_{k+1}: sub<=14 same slot; sub15 slot0 from slot1 (16->15);
            //                     sub15 slot1 = level 32 = 0 exactly
            M0r = s15 ? rM1r : rM0r;
            M0i = s15 ? rM1i : rM0i;
            M1r = s15 ? 0.f : rM1r;
            M1i = s15 ? 0.f : rM1i;
        }
    }

    // ---- coalesced output: block writes 16 voxels x 64 pulses ----
    __syncthreads();
    float4* out4 = (float4*)out;
    const int r = t >> 4;              // voxel row
    const int c = (t & 15) * 4;        // pulse col
    const float4 val = *(const float4*)&buf[r][c];   // row stride 272B, 16B-aligned
    out4[blockIdx.x * 256 + t] = val;
}

extern "C" void kernel_launch(void* const* d_in, const int* in_sizes, int n_in,
                              void* d_out, int out_size, void* d_ws, size_t ws_size,
                              hipStream_t stream) {
    const float* theta_re = (const float*)d_in[0];
    const float* theta_im = (const float*)d_in[1];
    const float* TRp      = (const float*)d_in[2];
    const float* qmaps    = (const float*)d_in[3];
    float* out = (float*)d_out;
    const int V = in_sizes[3] / 3;             // qmaps is [3, V, 1]
    epg_kernel<<<dim3(V / 16), dim3(256), 0, stream>>>(theta_re, theta_im, TRp, qmaps, out, V);
}

// Round 7
// 126.149 us; speedup vs baseline: 1.2280x; 1.2196x over previous
//
#include <hip/hip_runtime.h>
#include <math.h>

// EPG GRE F0, NP2=64 pulses, V voxels.
// 16 lanes per voxel: lane sub (0..15) holds levels k = 16*j + sub, j<2.
// k-shift = DPP row_ror; state held as packed float2 (re,im) so the complex
// 3x3 matvec + relaxation run on v_pk_fma_f32 / v_pk_mul_f32 (2 FMA per issue).
// ROUND 7: R2/R3/R4/R6 all ~100-110us with ~constant total VALU instructions
// across occupancy 17/30/54% => VALU-issue-throughput bound. This round halves
// issued ops via packed f32 and moves sqrt/PD out of the hot loop.
// Exactness (as R1-R6, passing): levels > p are exactly zero on the up-ramp;
// down-ramp junk at level >= 16 needs >= 16 down-shifts to reach F0 -> dead.

#define NP2 64
#define ROR1  0x121   // row_ror:1  : dest lane i <- lane (i-1) & 15
#define ROR15 0x12F   // row_ror:15 : dest lane i <- lane (i+1) & 15

typedef float v2f __attribute__((ext_vector_type(2)));

template<int CTRL>
__device__ __forceinline__ float rowrot(float x) {
    return __int_as_float(
        __builtin_amdgcn_mov_dpp(__float_as_int(x), CTRL, 0xF, 0xF, true));
}
template<int CTRL>
__device__ __forceinline__ v2f rowrot2(v2f v) {
    v2f r; r.x = rowrot<CTRL>(v.x); r.y = rowrot<CTRL>(v.y); return r;
}
__device__ __forceinline__ v2f fma2(v2f a, v2f b, v2f c) {
    return __builtin_elementwise_fma(a, b, c);
}
__device__ __forceinline__ v2f spl(float s) { v2f r; r.x = s; r.y = s; return r; }
__device__ __forceinline__ v2f ix(v2f v)   { v2f r; r.x = -v.y; r.y = v.x; return r; }  // i*v

__global__ __launch_bounds__(256, 4) void epg_kernel(
    const float* __restrict__ theta_re,
    const float* __restrict__ theta_im,
    const float* __restrict__ TRp,
    const float* __restrict__ qmaps,
    float* __restrict__ out, int V)
{
    const int t = threadIdx.x;
    const int sub = t & 15;           // lane within voxel group
    const int vloc = t >> 4;          // 0..15 local voxel
    const int v = blockIdx.x * 16 + vloc;

    __shared__ __align__(16) float rf[NP2][8]; // [p]: ca2, ca, t1, t2, t3, t4, h3, h4
    __shared__ v2f bufc[16][65];               // [vloc][pulse] raw F0 (re,im), +1 pad

    // ---- prologue: lane p computes pulse p's 8 RF coefficients (once) ----
    if (t < NP2) {
        const float tre = theta_re[t], tim = theta_im[t];
        const float a2 = tre * tre + tim * tim;
        const float inva = __frsqrt_rn(a2);        // |theta| >= 0.1
        const float a = a2 * inva;
        const float c = tre * inva, s = tim * inva;
        float sa, ca;
        __sincosf(a, &sa, &ca);
        const float ca2 = 0.5f + 0.5f * ca;        // cos^2(a/2)
        const float sa2 = 0.5f - 0.5f * ca;        // sin^2(a/2)
        const float t1 = (c * c - s * s) * sa2;    // cos(2phi)*sin^2(a/2)
        const float t2 = (2.f * c * s) * sa2;      // sin(2phi)*sin^2(a/2)
        const float t3 = s * sa;
        const float t4 = c * sa;
        rf[t][0] = ca2; rf[t][1] = ca; rf[t][2] = t1; rf[t][3] = t2;
        rf[t][4] = t3;  rf[t][5] = t4; rf[t][6] = 0.5f * t3; rf[t][7] = 0.5f * t4;
    }

    const float T1 = qmaps[V + v];
    const float T2 = qmaps[2 * V + v];
    const float tr = TRp[0];
    const v2f sE1 = spl(__expf(-tr / T1));
    const v2f sE2 = spl(__expf(-tr / T2));
    const float rE1s = (sub == 0) ? (1.0f - sE1.x) : 0.0f;

    // packed state: slot0 = levels sub, slot1 = levels 16+sub
    v2f P0 = spl(0.f), M0 = spl(0.f), Z0 = spl(0.f);
    v2f P1 = spl(0.f), M1 = spl(0.f), Z1 = spl(0.f);
    if (sub == 0) Z0.x = 1.0f;

    __syncthreads();

    const bool s0 = (sub == 0);
    const bool s15 = (sub == 15);

    // packed complex matvec:
    //   nP = ca2*P + t1*M + t2*(iM) + t3*Z - t4*(iZ)
    //   nM = t1*P - t2*(iP) + ca2*M + t3*Z + t4*(iZ)
    //   nZ = -h3*P - h4*(iP) - h3*M + h4*(iM) + ca*Z
#define MATVEC2(P, M, Z)                                                   \
    {                                                                      \
        const v2f p_ = P, m_ = M, z_ = Z;                                  \
        const v2f ip = ix(p_), im = ix(m_), iz = ix(z_);                   \
        P = fma2(sca2, p_, fma2(st1, m_, fma2(st2, im,                     \
                fma2(st3, z_, st4n * iz))));                               \
        M = fma2(st1, p_, fma2(st2n, ip, fma2(sca2, m_,                    \
                fma2(st3, z_, st4 * iz))));                                \
        Z = fma2(sh3n, p_, fma2(sh4n, ip, fma2(sh3n, m_,                   \
                fma2(sh4, im, sca * z_))));                                \
    }

    for (int p = 0; p < NP2; ++p) {
        const float4 c0 = *(const float4*)&rf[p][0];
        const float4 c1 = *(const float4*)&rf[p][4];
        const v2f sca2 = spl(c0.x), sca = spl(c0.y);
        const v2f st1 = spl(c0.z), st2 = spl(c0.w), st2n = spl(-c0.w);
        const v2f st3 = spl(c1.x), st4 = spl(c1.y), st4n = spl(-c1.y);
        const v2f sh4 = spl(c1.w), sh3n = spl(-c1.z), sh4n = spl(-c1.w);

        // ---- RF matvec, slot 0 (levels 0..15: always live) ----
        MATVEC2(P0, M0, Z0)
        // ---- slot 1 (levels 16..31: live iff 16 <= min(p,63-p)) ----
        if (p >= 16 && p <= 47) {
            MATVEC2(P1, M1, Z1)
        }
        // raw F0 = P'_0 (sub 0, slot 0); magnitude deferred to epilogue
        if (s0) bufc[vloc][p] = P0;

        if (p < NP2 - 1) {
            // ---- relaxation (full width, packed) ----
            P0 *= sE2; M0 *= sE2; Z0 *= sE1;
            P1 *= sE2; M1 *= sE2; Z1 *= sE1;
            Z0.x += rE1s;

            // ---- shift via DPP row rotate (pure VALU) ----
            const v2f rP0 = rowrot2<ROR1>(P0);
            const v2f rP1 = rowrot2<ROR1>(P1);
            const v2f rM0 = rowrot2<ROR15>(M0);
            const v2f rM1 = rowrot2<ROR15>(M1);
            // P_k <- E2*P'_{k-1}: sub>=1 same slot; sub0 slot1 from slot0 (15->16);
            //                     sub0 slot0 = conj(new M_0) = conj(E2*M'_1)
            P1.x = s0 ?  rP0.x : rP1.x;
            P1.y = s0 ?  rP0.y : rP1.y;
            P0.x = s0 ?  rM0.x : rP0.x;
            P0.y = s0 ? -rM0.y : rP0.y;
            // M_k <- E2*M'_{k+1}: sub<=14 same slot; sub15 slot0 from slot1 (16->15);
            //                     sub15 slot1 = level 32 = 0 exactly
            M0.x = s15 ? rM1.x : rM0.x;
            M0.y = s15 ? rM1.y : rM0.y;
            M1.x = s15 ? 0.f : rM1.x;
            M1.y = s15 ? 0.f : rM1.y;
        }
    }

    // ---- epilogue: magnitude * PD, coalesced float4 stores ----
    __syncthreads();
    const int r = t >> 4;              // voxel row
    const int c = (t & 15) * 4;        // pulse col
    const float PDr = qmaps[blockIdx.x * 16 + r];
    const v2f a = bufc[r][c], b = bufc[r][c + 1];
    const v2f d = bufc[r][c + 2], e = bufc[r][c + 3];
    float4 val;
    val.x = sqrtf(a.x * a.x + a.y * a.y) * PDr;
    val.y = sqrtf(b.x * b.x + b.y * b.y) * PDr;
    val.z = sqrtf(d.x * d.x + d.y * d.y) * PDr;
    val.w = sqrtf(e.x * e.x + e.y * e.y) * PDr;
    ((float4*)out)[blockIdx.x * 256 + t] = val;
}

extern "C" void kernel_launch(void* const* d_in, const int* in_sizes, int n_in,
                              void* d_out, int out_size, void* d_ws, size_t ws_size,
                              hipStream_t stream) {
    const float* theta_re = (const float*)d_in[0];
    const float* theta_im = (const float*)d_in[1];
    const float* TRp      = (const float*)d_in[2];
    const float* qmaps    = (const float*)d_in[3];
    float* out = (float*)d_out;
    const int V = in_sizes[3] / 3;             // qmaps is [3, V, 1]
    epg_kernel<<<dim3(V / 16), dim3(256), 0, stream>>>(theta_re, theta_im, TRp, qmaps, out, V);
}